// Round 8
// baseline (152.871 us; speedup 1.0000x reference)
//
#include <hip/hip_runtime.h>
#include <hip/hip_bf16.h>

#define NN 10000
#define NE 640000
#define D_IN 128
#define D_H 128
#define N_CLS 64
#define CAP 160    // per-node capacity (ushort): mean 64 sigma 8 -> +12 sigma
#define SENT 10000 // sentinel node id (zero row)
#define EB 625     // prep1 edge blocks: 625*256*4 == 640000
#define W01B 16    // prep1 tail blocks: W01 = W0@W1 (f32)
#define PB 40      // prep2 pad blocks: 40*256 >= NN
#define WPB 16     // prep2 tail blocks: Wp = W01@W2 bf16 pack (16*256 = 4096 slots)

// ---- bf16 helpers ----
__device__ __forceinline__ float blo(unsigned u) { return __uint_as_float(u << 16); }
__device__ __forceinline__ float bhi(unsigned u) { return __uint_as_float(u & 0xffff0000u); }
__device__ __forceinline__ unsigned short f2bf(float f) {
    unsigned u = __float_as_uint(f);
    return (unsigned short)((u + 0x7fffu + ((u >> 16) & 1u)) >> 16);
}
__device__ __forceinline__ unsigned packbf(float a, float b) {
    return (unsigned)f2bf(a) | ((unsigned)f2bf(b) << 16);
}

// ---- prep1: direct edge scatter (global atomics + 2B L2 stores) + W01 = W0@W1 ----
__global__ __launch_bounds__(256) void prep1(const int* __restrict__ src,
                                             const int* __restrict__ dst,
                                             int* __restrict__ cnt,
                                             unsigned short* __restrict__ colbuf,
                                             const float* __restrict__ W0,
                                             const float* __restrict__ W1,
                                             float* __restrict__ W01) {
    int bid = blockIdx.x;
    if (bid >= EB) {   // ---- W01 = W0@W1, f32 (16 blocks x 256 thr, 4 cols each) ----
        int t = (bid - EB) * 256 + threadIdx.x;   // 0..4095
        int i = t >> 5;            // row 0..127
        int jb = (t & 31) << 2;    // col group of 4
        float c0 = 0.f, c1 = 0.f, c2 = 0.f, c3 = 0.f;
        for (int k = 0; k < 128; ++k) {
            float a = W0[i * 128 + k];
            float4 b = *(const float4*)&W1[k * 128 + jb];
            c0 += a * b.x; c1 += a * b.y; c2 += a * b.z; c3 += a * b.w;
        }
        *(float4*)&W01[i * 128 + jb] = make_float4(c0, c1, c2, c3);
        return;
    }
    int t = bid * 256 + threadIdx.x;          // 0..159999, 4 edges each
    int4 s4 = ((const int4*)src)[t];
    int4 d4 = ((const int4*)dst)[t];
    int r;
    r = atomicAdd(&cnt[d4.x], 1); colbuf[(size_t)d4.x * CAP + r] = (unsigned short)s4.x;
    r = atomicAdd(&cnt[d4.y], 1); colbuf[(size_t)d4.y * CAP + r] = (unsigned short)s4.y;
    r = atomicAdd(&cnt[d4.z], 1); colbuf[(size_t)d4.z * CAP + r] = (unsigned short)s4.z;
    r = atomicAdd(&cnt[d4.w], 1); colbuf[(size_t)d4.w * CAP + r] = (unsigned short)s4.w;
}

// ---- prep2: pad colbuf to x32 + Wp = W01@W2 bf16 pack ----
__global__ __launch_bounds__(256) void prep2(int* __restrict__ cnt,
                                             unsigned short* __restrict__ colbuf,
                                             const float* __restrict__ W01,
                                             const float* __restrict__ W2,
                                             unsigned* __restrict__ wbp) {
    int bid = blockIdx.x;
    if (bid >= PB) {   // ---- Wp pack: 16 blocks x 256 thr = 4096 pack-slots (kp,j) ----
        int s = (bid - PB) * 256 + threadIdx.x;   // 0..4095
        int kp = s >> 6, j = s & 63;
        float c0 = 0.f, c1 = 0.f;
        const float* r0 = W01 + (2 * kp) * 128;
        const float* r1 = r0 + 128;
        for (int k = 0; k < 128; ++k) {
            float w2 = W2[k * 64 + j];
            c0 += r0[k] * w2;
            c1 += r1[k] * w2;
        }
        wbp[kp * 64 + j] = packbf(c0, c1);
        return;
    }
    int n = bid * 256 + threadIdx.x;
    if (n < NN) {
        int c = cnt[n];
        int pad = (32 - (c & 31)) & 31;    // pad to x32 for the unrolled gather
        unsigned short* b = colbuf + (size_t)n * CAP;
        for (int k = 0; k < pad; ++k) b[c + k] = (unsigned short)SENT;
        cnt[n] = c + pad;
    }
}

// ---- gemm0: g0 = feat @ Wp (dense, coalesced; 128 -> 64, bf16 out) ----
__global__ __launch_bounds__(256, 4) void gemm0(const float* __restrict__ feat,
                                                const unsigned* __restrict__ Wbp,
                                                unsigned short* __restrict__ g0) {
    __shared__ float xs[4][128];
    const int tid = threadIdx.x;
    const int wave = tid >> 6;
    const int lane = tid & 63;
    const int n = blockIdx.x * 4 + wave;
    float2 f = *(const float2*)&feat[(size_t)n * 128 + lane * 2];
    xs[wave][lane * 2]     = f.x;
    xs[wave][lane * 2 + 1] = f.y;
    __syncthreads();
    const int j = lane;
    float acc = 0.f;
    for (int k = 0; k < 128; k += 4) {
        unsigned wp0 = Wbp[(k >> 1) * 64 + j];
        unsigned wp1 = Wbp[((k >> 1) + 1) * 64 + j];
        float4 xv = *(const float4*)&xs[wave][k];
        acc += xv.x * blo(wp0) + xv.y * bhi(wp0) + xv.z * blo(wp1) + xv.w * bhi(wp1);
    }
    g0[(size_t)n * 64 + j] = f2bf(acc);
    if (blockIdx.x == 0 && tid < 16) {
        ((uint2*)(g0 + (size_t)SENT * 64))[tid] = make_uint2(0u, 0u);
    }
}

// ---- 64-d aggregate (32-row chunks): out_row(n) = in_row(n) + sum_neighbors -> bf16 ----
__global__ __launch_bounds__(256, 4) void agg64b(const uint4* __restrict__ tb4,
                                                 const int* __restrict__ cnt,
                                                 const unsigned short* __restrict__ colbuf,
                                                 unsigned short* __restrict__ tb2) {
    constexpr int M = 4;
    const int base = blockIdx.x * M;
    const int tid = threadIdx.x;
    const int wave = tid >> 6;
    const int lane = tid & 63;
    const int sub = lane >> 3;     // 0..7 : 8 rows per load instruction
    const int off = lane & 7;      // 16B slice within a 128B row

    const int n = __builtin_amdgcn_readfirstlane(base + wave);
    float a0, a1, a2, a3, a4, a5, a6, a7;
    if (sub == 0) {                // own row (eps=0)
        uint4 u = tb4[n * 8 + off];
        a0 = blo(u.x); a1 = bhi(u.x); a2 = blo(u.y); a3 = bhi(u.y);
        a4 = blo(u.z); a5 = bhi(u.z); a6 = blo(u.w); a7 = bhi(u.w);
    } else {
        a0 = a1 = a2 = a3 = a4 = a5 = a6 = a7 = 0.f;
    }
    const int NCH = __builtin_amdgcn_readfirstlane(cnt[n]) >> 5;   // 32-row chunks
    const uint2* cl = (const uint2*)(colbuf + (size_t)n * CAP);
    const int hi4 = sub >> 2;
    const int wsel = (sub >> 1) & 1;
    const int sh = (sub & 1) << 4;
    uint2 p0 = cl[0], p1 = cl[1], p2 = cl[2], p3 = cl[3];
    uint2 p4 = cl[4], p5 = cl[5], p6 = cl[6], p7 = cl[7];
    for (int c = 0; c < NCH; ++c) {
        unsigned q0 = hi4 ? (wsel ? p1.y : p1.x) : (wsel ? p0.y : p0.x);
        unsigned q1 = hi4 ? (wsel ? p3.y : p3.x) : (wsel ? p2.y : p2.x);
        unsigned q2 = hi4 ? (wsel ? p5.y : p5.x) : (wsel ? p4.y : p4.x);
        unsigned q3 = hi4 ? (wsel ? p7.y : p7.x) : (wsel ? p6.y : p6.x);
        int s0 = (int)((q0 >> sh) & 0xffffu);
        int s1 = (int)((q1 >> sh) & 0xffffu);
        int s2 = (int)((q2 >> sh) & 0xffffu);
        int s3 = (int)((q3 >> sh) & 0xffffu);
        uint4 u0 = tb4[s0 * 8 + off];
        uint4 u1 = tb4[s1 * 8 + off];
        uint4 u2 = tb4[s2 * 8 + off];
        uint4 u3 = tb4[s3 * 8 + off];
        {
            const uint2* nx = cl + 8 * (c + 1);   // safe over-read within workspace
            p0 = nx[0]; p1 = nx[1]; p2 = nx[2]; p3 = nx[3];
            p4 = nx[4]; p5 = nx[5]; p6 = nx[6]; p7 = nx[7];
        }
        a0 += (blo(u0.x) + blo(u1.x)) + (blo(u2.x) + blo(u3.x));
        a1 += (bhi(u0.x) + bhi(u1.x)) + (bhi(u2.x) + bhi(u3.x));
        a2 += (blo(u0.y) + blo(u1.y)) + (blo(u2.y) + blo(u3.y));
        a3 += (bhi(u0.y) + bhi(u1.y)) + (bhi(u2.y) + bhi(u3.y));
        a4 += (blo(u0.z) + blo(u1.z)) + (blo(u2.z) + blo(u3.z));
        a5 += (bhi(u0.z) + bhi(u1.z)) + (bhi(u2.z) + bhi(u3.z));
        a6 += (blo(u0.w) + blo(u1.w)) + (blo(u2.w) + blo(u3.w));
        a7 += (bhi(u0.w) + bhi(u1.w)) + (bhi(u2.w) + bhi(u3.w));
    }
    a0 += __shfl_xor(a0, 8); a0 += __shfl_xor(a0, 16); a0 += __shfl_xor(a0, 32);
    a1 += __shfl_xor(a1, 8); a1 += __shfl_xor(a1, 16); a1 += __shfl_xor(a1, 32);
    a2 += __shfl_xor(a2, 8); a2 += __shfl_xor(a2, 16); a2 += __shfl_xor(a2, 32);
    a3 += __shfl_xor(a3, 8); a3 += __shfl_xor(a3, 16); a3 += __shfl_xor(a3, 32);
    a4 += __shfl_xor(a4, 8); a4 += __shfl_xor(a4, 16); a4 += __shfl_xor(a4, 32);
    a5 += __shfl_xor(a5, 8); a5 += __shfl_xor(a5, 16); a5 += __shfl_xor(a5, 32);
    a6 += __shfl_xor(a6, 8); a6 += __shfl_xor(a6, 16); a6 += __shfl_xor(a6, 32);
    a7 += __shfl_xor(a7, 8); a7 += __shfl_xor(a7, 16); a7 += __shfl_xor(a7, 32);
    if (sub == 0) {
        unsigned short* o = tb2 + (size_t)n * 64 + 8 * off;
        *(uint4*)o = make_uint4(packbf(a0, a1), packbf(a2, a3),
                                packbf(a4, a5), packbf(a6, a7));
    }
    if (blockIdx.x == 0 && tid < 16) {
        ((uint2*)(tb2 + (size_t)SENT * 64))[tid] = make_uint2(0u, 0u);
    }
}

// ---- final 64-d aggregate (32-row chunks): f32 output ----
__global__ __launch_bounds__(256, 4) void agg64f(const uint4* __restrict__ tb4,
                                                 const int* __restrict__ cnt,
                                                 const unsigned short* __restrict__ colbuf,
                                                 float* __restrict__ outf) {
    constexpr int M = 4;
    const int base = blockIdx.x * M;
    const int tid = threadIdx.x;
    const int wave = tid >> 6;
    const int lane = tid & 63;
    const int sub = lane >> 3;
    const int off = lane & 7;

    const int n = __builtin_amdgcn_readfirstlane(base + wave);
    float a0, a1, a2, a3, a4, a5, a6, a7;
    if (sub == 0) {
        uint4 u = tb4[n * 8 + off];
        a0 = blo(u.x); a1 = bhi(u.x); a2 = blo(u.y); a3 = bhi(u.y);
        a4 = blo(u.z); a5 = bhi(u.z); a6 = blo(u.w); a7 = bhi(u.w);
    } else {
        a0 = a1 = a2 = a3 = a4 = a5 = a6 = a7 = 0.f;
    }
    const int NCH = __builtin_amdgcn_readfirstlane(cnt[n]) >> 5;
    const uint2* cl = (const uint2*)(colbuf + (size_t)n * CAP);
    const int hi4 = sub >> 2;
    const int wsel = (sub >> 1) & 1;
    const int sh = (sub & 1) << 4;
    uint2 p0 = cl[0], p1 = cl[1], p2 = cl[2], p3 = cl[3];
    uint2 p4 = cl[4], p5 = cl[5], p6 = cl[6], p7 = cl[7];
    for (int c = 0; c < NCH; ++c) {
        unsigned q0 = hi4 ? (wsel ? p1.y : p1.x) : (wsel ? p0.y : p0.x);
        unsigned q1 = hi4 ? (wsel ? p3.y : p3.x) : (wsel ? p2.y : p2.x);
        unsigned q2 = hi4 ? (wsel ? p5.y : p5.x) : (wsel ? p4.y : p4.x);
        unsigned q3 = hi4 ? (wsel ? p7.y : p7.x) : (wsel ? p6.y : p6.x);
        int s0 = (int)((q0 >> sh) & 0xffffu);
        int s1 = (int)((q1 >> sh) & 0xffffu);
        int s2 = (int)((q2 >> sh) & 0xffffu);
        int s3 = (int)((q3 >> sh) & 0xffffu);
        uint4 u0 = tb4[s0 * 8 + off];
        uint4 u1 = tb4[s1 * 8 + off];
        uint4 u2 = tb4[s2 * 8 + off];
        uint4 u3 = tb4[s3 * 8 + off];
        {
            const uint2* nx = cl + 8 * (c + 1);
            p0 = nx[0]; p1 = nx[1]; p2 = nx[2]; p3 = nx[3];
            p4 = nx[4]; p5 = nx[5]; p6 = nx[6]; p7 = nx[7];
        }
        a0 += (blo(u0.x) + blo(u1.x)) + (blo(u2.x) + blo(u3.x));
        a1 += (bhi(u0.x) + bhi(u1.x)) + (bhi(u2.x) + bhi(u3.x));
        a2 += (blo(u0.y) + blo(u1.y)) + (blo(u2.y) + blo(u3.y));
        a3 += (bhi(u0.y) + bhi(u1.y)) + (bhi(u2.y) + bhi(u3.y));
        a4 += (blo(u0.z) + blo(u1.z)) + (blo(u2.z) + blo(u3.z));
        a5 += (bhi(u0.z) + bhi(u1.z)) + (bhi(u2.z) + bhi(u3.z));
        a6 += (blo(u0.w) + blo(u1.w)) + (blo(u2.w) + blo(u3.w));
        a7 += (bhi(u0.w) + bhi(u1.w)) + (bhi(u2.w) + bhi(u3.w));
    }
    a0 += __shfl_xor(a0, 8); a0 += __shfl_xor(a0, 16); a0 += __shfl_xor(a0, 32);
    a1 += __shfl_xor(a1, 8); a1 += __shfl_xor(a1, 16); a1 += __shfl_xor(a1, 32);
    a2 += __shfl_xor(a2, 8); a2 += __shfl_xor(a2, 16); a2 += __shfl_xor(a2, 32);
    a3 += __shfl_xor(a3, 8); a3 += __shfl_xor(a3, 16); a3 += __shfl_xor(a3, 32);
    a4 += __shfl_xor(a4, 8); a4 += __shfl_xor(a4, 16); a4 += __shfl_xor(a4, 32);
    a5 += __shfl_xor(a5, 8); a5 += __shfl_xor(a5, 16); a5 += __shfl_xor(a5, 32);
    a6 += __shfl_xor(a6, 8); a6 += __shfl_xor(a6, 16); a6 += __shfl_xor(a6, 32);
    a7 += __shfl_xor(a7, 8); a7 += __shfl_xor(a7, 16); a7 += __shfl_xor(a7, 32);
    if (sub == 0) {
        float* o = outf + (size_t)n * N_CLS + 8 * off;
        *(float4*)o       = make_float4(a0, a1, a2, a3);
        *(float4*)(o + 4) = make_float4(a4, a5, a6, a7);
    }
}

extern "C" void kernel_launch(void* const* d_in, const int* in_sizes, int n_in,
                              void* d_out, int out_size, void* d_ws, size_t ws_size,
                              hipStream_t stream) {
    const float* feat = (const float*)d_in[0];
    const float* W0   = (const float*)d_in[1];
    const float* W1   = (const float*)d_in[2];
    const float* W2   = (const float*)d_in[3];
    const int*   src  = (const int*)d_in[4];
    const int*   dst  = (const int*)d_in[5];
    float* out = (float*)d_out;

    int* cnt               = (int*)d_ws;                          // NN (+32 pad)
    unsigned short* colbuf = (unsigned short*)(cnt + NN + 32);    // NN*CAP (+64 slack)
    unsigned* g0u          = (unsigned*)(colbuf + (size_t)NN * CAP + 64);  // (NN+1)*32
    unsigned* tbu          = g0u + (size_t)(NN + 1) * 32;         // (NN+1)*32
    unsigned* tb2u         = tbu + (size_t)(NN + 1) * 32;         // (NN+1)*32
    float* W01             = (float*)(tb2u + (size_t)(NN + 1) * 32); // 16384 f32
    unsigned* wbp          = (unsigned*)(W01 + 16384);            // 4096
    unsigned short* g0     = (unsigned short*)g0u;
    unsigned short* tb     = (unsigned short*)tbu;
    unsigned short* tb2    = (unsigned short*)tb2u;

    (void)hipMemsetAsync(cnt, 0, NN * sizeof(int), stream);
    prep1<<<EB + W01B, 256, 0, stream>>>(src, dst, cnt, colbuf, W0, W1, W01);
    prep2<<<PB + WPB, 256, 0, stream>>>(cnt, colbuf, W01, W2, wbp);

    gemm0<<<NN / 4, 256, 0, stream>>>(feat, wbp, g0);
    agg64b<<<NN / 4, 256, 0, stream>>>((const uint4*)g0, cnt, colbuf, tb);
    agg64b<<<NN / 4, 256, 0, stream>>>((const uint4*)tb, cnt, colbuf, tb2);
    agg64f<<<NN / 4, 256, 0, stream>>>((const uint4*)tb2, cnt, colbuf, out);
}